// Round 1
// baseline (208.640 us; speedup 1.0000x reference)
//
#include <hip/hip_runtime.h>

#define N 8192
#define D 512
#define MARGIN 0.3f

typedef __attribute__((ext_vector_type(8))) short bf16x8;   // 8 bf16 = 4 VGPRs
typedef __attribute__((ext_vector_type(4))) float f32x4;    // MFMA accumulator

// round-to-nearest-even fp32 -> bf16 (bit trick; inputs are normal floats)
__device__ __forceinline__ unsigned short f2bf(float f) {
    unsigned int u = __float_as_uint(f);
    u += 0x7fffu + ((u >> 16) & 1u);
    return (unsigned short)(u >> 16);
}

// async global->LDS, 16B per lane. LDS dest must be wave-uniform base + lane*16.
__device__ __forceinline__ void gload_lds16(const void* g, void* l) {
    __builtin_amdgcn_global_load_lds(
        (const __attribute__((address_space(1))) void*)g,
        (__attribute__((address_space(3))) void*)l,
        16, 0, 0);
}

// Kernel 1: per-row sum of squares (fp32, exact) + bf16 cast of X.
// One wave per row; block = 256 (4 waves); grid = N/4.
__global__ void prep_kernel(const float* __restrict__ x,
                            unsigned short* __restrict__ xb,
                            float* __restrict__ sq) {
    int w = threadIdx.x >> 6, lane = threadIdx.x & 63;
    int row = blockIdx.x * 4 + w;
    const float4* p = (const float4*)(x + (size_t)row * D) + lane * 2;
    float4 v0 = p[0], v1 = p[1];
    float s = v0.x * v0.x + v0.y * v0.y + v0.z * v0.z + v0.w * v0.w
            + v1.x * v1.x + v1.y * v1.y + v1.z * v1.z + v1.w * v1.w;
    bf16x8 pk;
    pk[0] = (short)f2bf(v0.x); pk[1] = (short)f2bf(v0.y);
    pk[2] = (short)f2bf(v0.z); pk[3] = (short)f2bf(v0.w);
    pk[4] = (short)f2bf(v1.x); pk[5] = (short)f2bf(v1.y);
    pk[6] = (short)f2bf(v1.z); pk[7] = (short)f2bf(v1.w);
    *(bf16x8*)(xb + (size_t)row * D + lane * 8) = pk;
    #pragma unroll
    for (int o = 32; o > 0; o >>= 1) s += __shfl_xor(s, o);
    if (lane == 0) sq[row] = s;
}

// Kernel 2: fused 128x128-tile bf16 MFMA Gram matrix + per-row masked max/min.
// Writes partial ap/an: [N/128 col-blocks][N rows].
__global__ __launch_bounds__(256)
void gemm_kernel(const unsigned short* __restrict__ xb,
                 const float* __restrict__ sq,
                 const int* __restrict__ tgt,
                 float* __restrict__ apv, float* __restrict__ anv) {
    __shared__ __align__(16) char smem_raw[32768];          // A/B tiles, reused for reduction
    __shared__ float sqI[128], sqJ[128];
    __shared__ int tI[128], tJ[128];
    unsigned short* Asm = (unsigned short*)smem_raw;        // [128][64] bf16
    unsigned short* Bsm = Asm + 128 * 64;                   // [128][64] bf16
    float* redAp = (float*)smem_raw;                        // [128][32] (after K loop)
    float* redAn = redAp + 128 * 32;

    const int tid = threadIdx.x;
    const int w = tid >> 6, lane = tid & 63, q = lane >> 4, c = lane & 15;
    const int wm = w & 1, wn = w >> 1;                      // 2x2 wave grid, 64x64 each
    const int rowBase = blockIdx.y * 128, colBase = blockIdx.x * 128;

    if (tid < 128) { sqI[tid] = sq[rowBase + tid]; tI[tid] = tgt[rowBase + tid]; }
    else { int t = tid - 128; sqJ[t] = sq[colBase + t]; tJ[t] = tgt[colBase + t]; }

    const unsigned short* Ag = xb + (size_t)rowBase * D;
    const unsigned short* Bg = xb + (size_t)colBase * D;

    f32x4 acc[4][4] = {};

    for (int k0 = 0; k0 < D; k0 += 64) {
        // stage A,B tiles: 128x64 bf16 each = 1024 16B chunks = 256 thr x 4
        #pragma unroll
        for (int s = 0; s < 4; s++) {
            int chunk = s * 256 + tid;
            int r = chunk >> 3, c8 = (chunk & 7) << 3;
            gload_lds16(Ag + (size_t)r * D + k0 + c8, Asm + chunk * 8);
            gload_lds16(Bg + (size_t)r * D + k0 + c8, Bsm + chunk * 8);
        }
        __syncthreads();   // compiler drains vmcnt before s_barrier
        #pragma unroll
        for (int kk = 0; kk < 64; kk += 32) {
            bf16x8 af[4], bfr[4];
            #pragma unroll
            for (int t = 0; t < 4; t++) {
                af[t]  = *(const bf16x8*)(Asm + (wm * 64 + t * 16 + c) * 64 + kk + q * 8);
                bfr[t] = *(const bf16x8*)(Bsm + (wn * 64 + t * 16 + c) * 64 + kk + q * 8);
            }
            #pragma unroll
            for (int tm = 0; tm < 4; tm++)
                #pragma unroll
                for (int tn = 0; tn < 4; tn++)
                    acc[tm][tn] = __builtin_amdgcn_mfma_f32_16x16x32_bf16(
                        af[tm], bfr[tn], acc[tm][tn], 0, 0, 0);
        }
        __syncthreads();
    }

    // Epilogue: C/D layout col = lane&15, row = (lane>>4)*4 + reg.
    // Per lane: reduce over tn (4 cols stride 16) -> 16 (tm,reg) row slots.
    float apl[4][4], anl[4][4];
    #pragma unroll
    for (int tm = 0; tm < 4; tm++) {
        #pragma unroll
        for (int r = 0; r < 4; r++) {
            int row_l = wm * 64 + tm * 16 + q * 4 + r;
            float si = sqI[row_l]; int ti = tI[row_l];
            float ap = -1e30f, an = 1e30f;
            #pragma unroll
            for (int tn = 0; tn < 4; tn++) {
                int col_l = wn * 64 + tn * 16 + c;
                float d2 = si + sqJ[col_l] - 2.0f * acc[tm][tn][r];
                float dist = sqrtf(fmaxf(d2, 1e-12f));
                if (ti == tJ[col_l]) ap = fmaxf(ap, dist);
                else                 an = fminf(an, dist);
            }
            apl[tm][r] = ap; anl[tm][r] = an;
        }
    }
    // K loop ended with __syncthreads(): safe to reuse Asm/Bsm as redAp/redAn.
    #pragma unroll
    for (int tm = 0; tm < 4; tm++)
        #pragma unroll
        for (int r = 0; r < 4; r++) {
            int row_l = wm * 64 + tm * 16 + q * 4 + r;
            redAp[row_l * 32 + wn * 16 + c] = apl[tm][r];
            redAn[row_l * 32 + wn * 16 + c] = anl[tm][r];
        }
    __syncthreads();
    if (tid < 128) {
        float ap = -1e30f, an = 1e30f;
        #pragma unroll 8
        for (int u = 0; u < 32; u++) {
            ap = fmaxf(ap, redAp[tid * 32 + u]);
            an = fminf(an, redAn[tid * 32 + u]);
        }
        apv[(size_t)blockIdx.x * N + rowBase + tid] = ap;
        anv[(size_t)blockIdx.x * N + rowBase + tid] = an;
    }
}

// Kernel 3: per-row final max/min over 64 partials + relu; block partial sums.
__global__ void reduce_kernel(const float* __restrict__ apv,
                              const float* __restrict__ anv,
                              float* __restrict__ bsum) {
    int tid = threadIdx.x;
    int row = blockIdx.x * 256 + tid;
    float ap = -1e30f, an = 1e30f;
    #pragma unroll 8
    for (int j = 0; j < N / 128; j++) {
        ap = fmaxf(ap, apv[(size_t)j * N + row]);
        an = fminf(an, anv[(size_t)j * N + row]);
    }
    float v = fmaxf(ap - an + MARGIN, 0.0f);
    #pragma unroll
    for (int o = 32; o > 0; o >>= 1) v += __shfl_xor(v, o);
    __shared__ float ss[4];
    if ((tid & 63) == 0) ss[tid >> 6] = v;
    __syncthreads();
    if (tid == 0) bsum[blockIdx.x] = ss[0] + ss[1] + ss[2] + ss[3];
}

// Kernel 4: sum 32 block sums, write mean. (d_out is poisoned pre-launch, so
// it must be written unconditionally here, not atomically accumulated.)
__global__ void final_kernel(const float* __restrict__ bsum, float* __restrict__ out) {
    float v = (threadIdx.x < 32) ? bsum[threadIdx.x] : 0.0f;
    #pragma unroll
    for (int o = 32; o > 0; o >>= 1) v += __shfl_xor(v, o);
    if (threadIdx.x == 0) out[0] = v * (1.0f / (float)N);
}

extern "C" void kernel_launch(void* const* d_in, const int* in_sizes, int n_in,
                              void* d_out, int out_size, void* d_ws, size_t ws_size,
                              hipStream_t stream) {
    const float* x  = (const float*)d_in[0];
    const int* tgt  = (const int*)d_in[1];
    float* out      = (float*)d_out;

    char* ws = (char*)d_ws;
    unsigned short* xb = (unsigned short*)ws;                       // 8 MB bf16 X
    float* sq  = (float*)(ws + (size_t)N * D * 2);                  // 32 KB
    float* apv = sq + N;                                            // 2 MB [64][N]
    float* anv = apv + (N / 128) * N;                               // 2 MB [64][N]
    float* bsum = anv + (N / 128) * N;                              // 128 B

    prep_kernel<<<N / 4, 256, 0, stream>>>(x, xb, sq);
    gemm_kernel<<<dim3(N / 128, N / 128), 256, 0, stream>>>(xb, sq, tgt, apv, anv);
    reduce_kernel<<<N / 256, 256, 0, stream>>>(apv, anv, bsum);
    final_kernel<<<1, 64, 0, stream>>>(bsum, out);
}

// Round 2
// 155.493 us; speedup vs baseline: 1.3418x; 1.3418x over previous
//
#include <hip/hip_runtime.h>

#define N 8192
#define D 512
#define NB (N / 128)          // 64 row/col blocks
#define MARGIN 0.3f

typedef __attribute__((ext_vector_type(8))) short bf16x8;   // 8 bf16 = 4 VGPRs
typedef __attribute__((ext_vector_type(4))) float f32x4;    // MFMA accumulator

// round-to-nearest-even fp32 -> bf16
__device__ __forceinline__ unsigned short f2bf(float f) {
    unsigned int u = __float_as_uint(f);
    u += 0x7fffu + ((u >> 16) & 1u);
    return (unsigned short)(u >> 16);
}

// async global->LDS, 16B per lane; LDS dest = wave-uniform base + lane*16.
__device__ __forceinline__ void gload_lds16(const void* g, void* l) {
    __builtin_amdgcn_global_load_lds(
        (const __attribute__((address_space(1))) void*)g,
        (__attribute__((address_space(3))) void*)l,
        16, 0, 0);
}

// Kernel 1: per-row fp32 sum-of-squares (exact) + bf16 cast of X.
__global__ void prep_kernel(const float* __restrict__ x,
                            unsigned short* __restrict__ xb,
                            float* __restrict__ sq) {
    int w = threadIdx.x >> 6, lane = threadIdx.x & 63;
    int row = blockIdx.x * 4 + w;
    const float4* p = (const float4*)(x + (size_t)row * D) + lane * 2;
    float4 v0 = p[0], v1 = p[1];
    float s = v0.x * v0.x + v0.y * v0.y + v0.z * v0.z + v0.w * v0.w
            + v1.x * v1.x + v1.y * v1.y + v1.z * v1.z + v1.w * v1.w;
    bf16x8 pk;
    pk[0] = (short)f2bf(v0.x); pk[1] = (short)f2bf(v0.y);
    pk[2] = (short)f2bf(v0.z); pk[3] = (short)f2bf(v0.w);
    pk[4] = (short)f2bf(v1.x); pk[5] = (short)f2bf(v1.y);
    pk[6] = (short)f2bf(v1.z); pk[7] = (short)f2bf(v1.w);
    *(bf16x8*)(xb + (size_t)row * D + lane * 8) = pk;
    #pragma unroll
    for (int o = 32; o > 0; o >>= 1) s += __shfl_xor(s, o);
    if (lane == 0) sq[row] = s;
}

// Kernel 2: triangular-grid fused Gram tile + masked row AND column reductions.
// Tile (bi,bj), bi<=bj. Row-reduce -> slot bj of rows bi*128..; if bi!=bj,
// col-reduce (dist/mask symmetric) -> slot bi of rows bj*128.. .
// LDS tiles XOR-swizzled: logical chunk (r,kc) stored at r*8 + (kc ^ (r&7)),
// achieved by permuting the *global source* per lane (global_load_lds dest is
// forced contiguous). Makes both staging and ds_read_b128 conflict-free.
__global__ __launch_bounds__(256)
void gemm_kernel(const unsigned short* __restrict__ xb,
                 const float* __restrict__ sq,
                 const int* __restrict__ tgt,
                 float* __restrict__ apv, float* __restrict__ anv) {
    __shared__ __align__(16) char smem_raw[34816];
    __shared__ float sqI[128], sqJ[128];
    __shared__ int tI[128], tJ[128];
    unsigned short* Asm = (unsigned short*)smem_raw;        // [128][64] bf16, swizzled
    unsigned short* Bsm = Asm + 128 * 64;
    float* redAp = (float*)smem_raw;                        // [128][34] (stride-pad)
    float* redAn = redAp + 128 * 34;                        // exactly 34816 B total
    float* colAp = (float*)smem_raw;                        // [128][10] (after row phase)
    float* colAn = colAp + 128 * 10;

    const int tid = threadIdx.x;
    const int w = tid >> 6, lane = tid & 63, q = lane >> 4, c = lane & 15;
    const int wm = w & 1, wn = w >> 1;                      // 2x2 wave grid, 64x64 each

    // decode triangular tile index: (bi,bj) with bi<=bj
    int rem = blockIdx.x, bi = 0;
    while (rem >= NB - bi) { rem -= NB - bi; bi++; }
    const int bj = bi + rem;
    const int rowBase = bi * 128, colBase = bj * 128;

    if (tid < 128) { sqI[tid] = sq[rowBase + tid]; tI[tid] = tgt[rowBase + tid]; }
    else { int u = tid - 128; sqJ[u] = sq[colBase + u]; tJ[u] = tgt[colBase + u]; }

    const unsigned short* Ag = xb + (size_t)rowBase * D;
    const unsigned short* Bg = xb + (size_t)colBase * D;

    f32x4 acc[4][4] = {};

    for (int k0 = 0; k0 < D; k0 += 64) {
        #pragma unroll
        for (int s = 0; s < 4; s++) {
            int p = s * 256 + tid;
            int r = p >> 3, kc = (p & 7) ^ (r & 7);         // source-chunk permutation
            gload_lds16(Ag + (size_t)r * D + k0 + kc * 8, Asm + p * 8);
            gload_lds16(Bg + (size_t)r * D + k0 + kc * 8, Bsm + p * 8);
        }
        __syncthreads();
        #pragma unroll
        for (int kk = 0; kk < 64; kk += 32) {
            const int kx = ((kk >> 3) + q) ^ (c & 7);       // swizzled chunk (row&7 == c&7)
            bf16x8 af[4], bfr[4];
            #pragma unroll
            for (int t = 0; t < 4; t++) {
                int ra = wm * 64 + t * 16 + c;
                int rb = wn * 64 + t * 16 + c;
                af[t]  = *(const bf16x8*)(Asm + ra * 64 + kx * 8);
                bfr[t] = *(const bf16x8*)(Bsm + rb * 64 + kx * 8);
            }
            #pragma unroll
            for (int tm = 0; tm < 4; tm++)
                #pragma unroll
                for (int tn = 0; tn < 4; tn++)
                    acc[tm][tn] = __builtin_amdgcn_mfma_f32_16x16x32_bf16(
                        af[tm], bfr[tn], acc[tm][tn], 0, 0, 0);
        }
        __syncthreads();
    }

    // Epilogue. C/D layout: col = lane&15 (per tn), row = q*4 + reg (per tm).
    float apc[4] = {-1e30f, -1e30f, -1e30f, -1e30f};
    float anc[4] = {1e30f, 1e30f, 1e30f, 1e30f};
    #pragma unroll
    for (int tm = 0; tm < 4; tm++) {
        #pragma unroll
        for (int r = 0; r < 4; r++) {
            int row_l = wm * 64 + tm * 16 + q * 4 + r;
            float si = sqI[row_l]; int ti = tI[row_l];
            float ap = -1e30f, an = 1e30f;
            #pragma unroll
            for (int tn = 0; tn < 4; tn++) {
                int col_l = wn * 64 + tn * 16 + c;
                float d2 = si + sqJ[col_l] - 2.0f * acc[tm][tn][r];
                float dist = sqrtf(fmaxf(d2, 1e-12f));
                if (ti == tJ[col_l]) {
                    ap = fmaxf(ap, dist); apc[tn] = fmaxf(apc[tn], dist);
                } else {
                    an = fminf(an, dist); anc[tn] = fminf(anc[tn], dist);
                }
            }
            redAp[row_l * 34 + wn * 16 + c] = ap;           // K loop ended in barrier:
            redAn[row_l * 34 + wn * 16 + c] = an;           // tiles dead, safe reuse
        }
    }
    __syncthreads();
    if (tid < 128) {
        float ap = -1e30f, an = 1e30f;
        #pragma unroll 8
        for (int u = 0; u < 32; u++) {
            ap = fmaxf(ap, redAp[tid * 34 + u]);
            an = fminf(an, redAn[tid * 34 + u]);
        }
        apv[(size_t)bj * N + rowBase + tid] = ap;
        anv[(size_t)bj * N + rowBase + tid] = an;
    }
    if (bi != bj) {                                         // wave-uniform branch
        __syncthreads();                                    // row-phase readers done
        #pragma unroll
        for (int tn = 0; tn < 4; tn++) {
            int col_l = wn * 64 + tn * 16 + c;
            colAp[col_l * 10 + wm * 4 + q] = apc[tn];
            colAn[col_l * 10 + wm * 4 + q] = anc[tn];
        }
        __syncthreads();
        if (tid < 128) {
            float ap = -1e30f, an = 1e30f;
            #pragma unroll
            for (int u = 0; u < 8; u++) {
                ap = fmaxf(ap, colAp[tid * 10 + u]);
                an = fminf(an, colAn[tid * 10 + u]);
            }
            apv[(size_t)bi * N + colBase + tid] = ap;
            anv[(size_t)bi * N + colBase + tid] = an;
        }
    }
}

// Kernel 3: per-row final max/min over 64 slot partials + relu; block sums.
__global__ void reduce_kernel(const float* __restrict__ apv,
                              const float* __restrict__ anv,
                              float* __restrict__ bsum) {
    int tid = threadIdx.x;
    int row = blockIdx.x * 256 + tid;
    float ap = -1e30f, an = 1e30f;
    #pragma unroll 8
    for (int j = 0; j < NB; j++) {
        ap = fmaxf(ap, apv[(size_t)j * N + row]);
        an = fminf(an, anv[(size_t)j * N + row]);
    }
    float v = fmaxf(ap - an + MARGIN, 0.0f);
    #pragma unroll
    for (int o = 32; o > 0; o >>= 1) v += __shfl_xor(v, o);
    __shared__ float ss[4];
    if ((tid & 63) == 0) ss[tid >> 6] = v;
    __syncthreads();
    if (tid == 0) bsum[blockIdx.x] = ss[0] + ss[1] + ss[2] + ss[3];
}

// Kernel 4: sum 32 block sums -> mean (unconditional write; d_out is poisoned).
__global__ void final_kernel(const float* __restrict__ bsum, float* __restrict__ out) {
    float v = (threadIdx.x < 32) ? bsum[threadIdx.x] : 0.0f;
    #pragma unroll
    for (int o = 32; o > 0; o >>= 1) v += __shfl_xor(v, o);
    if (threadIdx.x == 0) out[0] = v * (1.0f / (float)N);
}

extern "C" void kernel_launch(void* const* d_in, const int* in_sizes, int n_in,
                              void* d_out, int out_size, void* d_ws, size_t ws_size,
                              hipStream_t stream) {
    const float* x  = (const float*)d_in[0];
    const int* tgt  = (const int*)d_in[1];
    float* out      = (float*)d_out;

    char* ws = (char*)d_ws;
    unsigned short* xb = (unsigned short*)ws;                       // 8 MB bf16 X
    float* sq  = (float*)(ws + (size_t)N * D * 2);                  // 32 KB
    float* apv = sq + N;                                            // 2 MB [64][N]
    float* anv = apv + (size_t)NB * N;                              // 2 MB [64][N]
    float* bsum = anv + (size_t)NB * N;                             // 128 B

    prep_kernel<<<N / 4, 256, 0, stream>>>(x, xb, sq);
    gemm_kernel<<<NB * (NB + 1) / 2, 256, 0, stream>>>(xb, sq, tgt, apv, anv);
    reduce_kernel<<<N / 256, 256, 0, stream>>>(apv, anv, bsum);
    final_kernel<<<1, 64, 0, stream>>>(bsum, out);
}

// Round 3
// 134.777 us; speedup vs baseline: 1.5480x; 1.1537x over previous
//
#include <hip/hip_runtime.h>

#define N 8192
#define D 512
#define NB (N / 128)          // 64 row/col blocks
#define MARGIN 0.3f

typedef __attribute__((ext_vector_type(8))) short bf16x8;   // 8 bf16 = 4 VGPRs
typedef __attribute__((ext_vector_type(4))) float f32x4;    // MFMA accumulator

// round-to-nearest-even fp32 -> bf16
__device__ __forceinline__ unsigned short f2bf(float f) {
    unsigned int u = __float_as_uint(f);
    u += 0x7fffu + ((u >> 16) & 1u);
    return (unsigned short)(u >> 16);
}

// async global->LDS, 16B per lane; LDS dest = wave-uniform base + lane*16.
__device__ __forceinline__ void gload_lds16(const void* g, void* l) {
    __builtin_amdgcn_global_load_lds(
        (const __attribute__((address_space(1))) void*)g,
        (__attribute__((address_space(3))) void*)l,
        16, 0, 0);
}

// Kernel 1: per-row fp32 sum-of-squares (exact) + bf16 cast of X.
__global__ void prep_kernel(const float* __restrict__ x,
                            unsigned short* __restrict__ xb,
                            float* __restrict__ sq) {
    int w = threadIdx.x >> 6, lane = threadIdx.x & 63;
    int row = blockIdx.x * 4 + w;
    const float4* p = (const float4*)(x + (size_t)row * D) + lane * 2;
    float4 v0 = p[0], v1 = p[1];
    float s = v0.x * v0.x + v0.y * v0.y + v0.z * v0.z + v0.w * v0.w
            + v1.x * v1.x + v1.y * v1.y + v1.z * v1.z + v1.w * v1.w;
    bf16x8 pk;
    pk[0] = (short)f2bf(v0.x); pk[1] = (short)f2bf(v0.y);
    pk[2] = (short)f2bf(v0.z); pk[3] = (short)f2bf(v0.w);
    pk[4] = (short)f2bf(v1.x); pk[5] = (short)f2bf(v1.y);
    pk[6] = (short)f2bf(v1.z); pk[7] = (short)f2bf(v1.w);
    *(bf16x8*)(xb + (size_t)row * D + lane * 8) = pk;
    #pragma unroll
    for (int o = 32; o > 0; o >>= 1) s += __shfl_xor(s, o);
    if (lane == 0) sq[row] = s;
}

// Kernel 2: triangular-grid fused Gram tile + masked row AND column reductions.
// Selection runs in d^2-space (sqrt is monotonic -> moved to reduce_kernel).
// Row-side key:  rk = sj[col] - 2*p   (si const per row, added back at writeout)
// Col-side key:  ck = si[row] - 2*p   (sj const per col, added back at writeout)
__global__ __launch_bounds__(256)
void gemm_kernel(const unsigned short* __restrict__ xb,
                 const float* __restrict__ sq,
                 const int* __restrict__ tgt,
                 float* __restrict__ apv, float* __restrict__ anv) {
    __shared__ __align__(16) char smem_raw[34816];
    __shared__ float sqI[128], sqJ[128];
    __shared__ int tI[128], tJ[128];
    unsigned short* Asm = (unsigned short*)smem_raw;        // [128][64] bf16, swizzled
    unsigned short* Bsm = Asm + 128 * 64;
    float* redAp = (float*)smem_raw;                        // [128][34] (stride-pad)
    float* redAn = redAp + 128 * 34;                        // exactly 34816 B total
    float* colAp = (float*)smem_raw;                        // [128][10] (after row phase)
    float* colAn = colAp + 128 * 10;

    const int tid = threadIdx.x;
    const int w = tid >> 6, lane = tid & 63, q = lane >> 4, c = lane & 15;
    const int wm = w & 1, wn = w >> 1;                      // 2x2 wave grid, 64x64 each

    // decode triangular tile index: (bi,bj) with bi<=bj
    int rem = blockIdx.x, bi = 0;
    while (rem >= NB - bi) { rem -= NB - bi; bi++; }
    const int bj = bi + rem;
    const int rowBase = bi * 128, colBase = bj * 128;

    if (tid < 128) { sqI[tid] = sq[rowBase + tid]; tI[tid] = tgt[rowBase + tid]; }
    else { int u = tid - 128; sqJ[u] = sq[colBase + u]; tJ[u] = tgt[colBase + u]; }

    const unsigned short* Ag = xb + (size_t)rowBase * D;
    const unsigned short* Bg = xb + (size_t)colBase * D;

    f32x4 acc[4][4] = {};

    for (int k0 = 0; k0 < D; k0 += 64) {
        #pragma unroll
        for (int s = 0; s < 4; s++) {
            int p = s * 256 + tid;
            int r = p >> 3, kc = (p & 7) ^ (r & 7);         // source-chunk permutation
            gload_lds16(Ag + (size_t)r * D + k0 + kc * 8, Asm + p * 8);
            gload_lds16(Bg + (size_t)r * D + k0 + kc * 8, Bsm + p * 8);
        }
        __syncthreads();
        #pragma unroll
        for (int kk = 0; kk < 64; kk += 32) {
            const int kx = ((kk >> 3) + q) ^ (c & 7);       // swizzled chunk
            bf16x8 af[4], bfr[4];
            #pragma unroll
            for (int t = 0; t < 4; t++) {
                int ra = wm * 64 + t * 16 + c;
                int rb = wn * 64 + t * 16 + c;
                af[t]  = *(const bf16x8*)(Asm + ra * 64 + kx * 8);
                bfr[t] = *(const bf16x8*)(Bsm + rb * 64 + kx * 8);
            }
            #pragma unroll
            for (int tm = 0; tm < 4; tm++)
                #pragma unroll
                for (int tn = 0; tn < 4; tn++)
                    acc[tm][tn] = __builtin_amdgcn_mfma_f32_16x16x32_bf16(
                        af[tm], bfr[tn], acc[tm][tn], 0, 0, 0);
        }
        __syncthreads();
    }

    // Epilogue. C/D layout: col = lane&15 (per tn), row = q*4 + reg (per tm).
    float sjc[4]; int tj4[4];
    #pragma unroll
    for (int tn = 0; tn < 4; tn++) {
        int col_l = wn * 64 + tn * 16 + c;
        sjc[tn] = sqJ[col_l]; tj4[tn] = tJ[col_l];
    }
    float apc[4] = {-1e30f, -1e30f, -1e30f, -1e30f};
    float anc[4] = {1e30f, 1e30f, 1e30f, 1e30f};
    #pragma unroll
    for (int tm = 0; tm < 4; tm++) {
        #pragma unroll
        for (int r = 0; r < 4; r++) {
            int row_l = wm * 64 + tm * 16 + q * 4 + r;
            float si = sqI[row_l]; int ti = tI[row_l];
            float rp = -1e30f, rn = 1e30f;
            #pragma unroll
            for (int tn = 0; tn < 4; tn++) {
                float p = acc[tm][tn][r];
                bool same = (ti == tj4[tn]);
                float rk = fmaf(-2.0f, p, sjc[tn]);         // row-side key
                float ck = fmaf(-2.0f, p, si);              // col-side key
                rp = fmaxf(rp, same ? rk : -1e30f);
                rn = fminf(rn, same ? 1e30f : rk);
                apc[tn] = fmaxf(apc[tn], same ? ck : -1e30f);
                anc[tn] = fminf(anc[tn], same ? 1e30f : ck);
            }
            redAp[row_l * 34 + wn * 16 + c] = rp;           // K loop ended in barrier:
            redAn[row_l * 34 + wn * 16 + c] = rn;           // tiles dead, safe reuse
        }
    }
    __syncthreads();
    if (tid < 128) {
        float ap = -1e30f, an = 1e30f;
        #pragma unroll 8
        for (int u = 0; u < 32; u++) {
            ap = fmaxf(ap, redAp[tid * 34 + u]);
            an = fminf(an, redAn[tid * 34 + u]);
        }
        apv[(size_t)bj * N + rowBase + tid] = sqI[tid] + ap;   // restore true d^2
        anv[(size_t)bj * N + rowBase + tid] = sqI[tid] + an;
    }
    if (bi != bj) {                                         // wave-uniform branch
        __syncthreads();                                    // row-phase readers done
        #pragma unroll
        for (int tn = 0; tn < 4; tn++) {
            int col_l = wn * 64 + tn * 16 + c;
            colAp[col_l * 10 + wm * 4 + q] = apc[tn];
            colAn[col_l * 10 + wm * 4 + q] = anc[tn];
        }
        __syncthreads();
        if (tid < 128) {
            float ap = -1e30f, an = 1e30f;
            #pragma unroll
            for (int u = 0; u < 8; u++) {
                ap = fmaxf(ap, colAp[tid * 10 + u]);
                an = fminf(an, colAn[tid * 10 + u]);
            }
            apv[(size_t)bi * N + colBase + tid] = sqJ[tid] + ap;
            anv[(size_t)bi * N + colBase + tid] = sqJ[tid] + an;
        }
    }
}

// Kernel 3: per-row final max/min over 64 d^2 partials; clamp+sqrt here
// (selection in d^2-space is exact: sqrt is monotonic).
__global__ void reduce_kernel(const float* __restrict__ apv,
                              const float* __restrict__ anv,
                              float* __restrict__ bsum) {
    int tid = threadIdx.x;
    int row = blockIdx.x * 256 + tid;
    float ap = -1e30f, an = 1e30f;
    #pragma unroll 8
    for (int j = 0; j < NB; j++) {
        ap = fmaxf(ap, apv[(size_t)j * N + row]);
        an = fminf(an, anv[(size_t)j * N + row]);
    }
    float dap = sqrtf(fmaxf(ap, 1e-12f));
    float dan = sqrtf(fmaxf(an, 1e-12f));
    float v = fmaxf(dap - dan + MARGIN, 0.0f);
    #pragma unroll
    for (int o = 32; o > 0; o >>= 1) v += __shfl_xor(v, o);
    __shared__ float ss[4];
    if ((tid & 63) == 0) ss[tid >> 6] = v;
    __syncthreads();
    if (tid == 0) bsum[blockIdx.x] = ss[0] + ss[1] + ss[2] + ss[3];
}

// Kernel 4: sum 32 block sums -> mean (unconditional write; d_out is poisoned).
__global__ void final_kernel(const float* __restrict__ bsum, float* __restrict__ out) {
    float v = (threadIdx.x < 32) ? bsum[threadIdx.x] : 0.0f;
    #pragma unroll
    for (int o = 32; o > 0; o >>= 1) v += __shfl_xor(v, o);
    if (threadIdx.x == 0) out[0] = v * (1.0f / (float)N);
}

extern "C" void kernel_launch(void* const* d_in, const int* in_sizes, int n_in,
                              void* d_out, int out_size, void* d_ws, size_t ws_size,
                              hipStream_t stream) {
    const float* x  = (const float*)d_in[0];
    const int* tgt  = (const int*)d_in[1];
    float* out      = (float*)d_out;

    char* ws = (char*)d_ws;
    unsigned short* xb = (unsigned short*)ws;                       // 8 MB bf16 X
    float* sq  = (float*)(ws + (size_t)N * D * 2);                  // 32 KB
    float* apv = sq + N;                                            // 2 MB [64][N]
    float* anv = apv + (size_t)NB * N;                              // 2 MB [64][N]
    float* bsum = anv + (size_t)NB * N;                             // 128 B

    prep_kernel<<<N / 4, 256, 0, stream>>>(x, xb, sq);
    gemm_kernel<<<NB * (NB + 1) / 2, 256, 0, stream>>>(xb, sq, tgt, apv, anv);
    reduce_kernel<<<N / 256, 256, 0, stream>>>(apv, anv, bsum);
    final_kernel<<<1, 64, 0, stream>>>(bsum, out);
}